// Round 16
// baseline (102.868 us; speedup 1.0000x reference)
//
#include <hip/hip_runtime.h>
#include <math.h>

#define H     2048
#define NE    64
#define KTOP  8
#define NTOK  16384
#define TOKB  64
#define STEPS 64                       // full K (2048) / 32

typedef __attribute__((ext_vector_type(8))) __bf16 bf16x8;
typedef __attribute__((ext_vector_type(8))) unsigned short us8;
typedef __attribute__((ext_vector_type(4))) float f32x4;

__device__ __forceinline__ unsigned short f2bf(float f) {
    unsigned u = __builtin_bit_cast(unsigned, f);
    return (unsigned short)((u + 0x7FFFu + ((u >> 16) & 1u)) >> 16);  // RNE
}

// volatile asm global loads: compiler cannot sink/reorder/drain them.
#define GLOAD_F4(dst, ptr, OFF)                                        \
    asm volatile("global_load_dwordx4 %0, %1, off offset:%2"           \
                 : "=v"(dst) : "v"(ptr), "i"(OFF))
// non-temporal variant: bypasses L1 (keeps it free for B-tile reuse)
#define GLOAD_F4_NT(dst, ptr, OFF)                                     \
    asm volatile("global_load_dwordx4 %0, %1, off offset:%2 nt"        \
                 : "=v"(dst) : "v"(ptr), "i"(OFF))
#define WAITV(N)                                                       \
    do { asm volatile("s_waitcnt vmcnt(%0)" :: "i"(N));                \
         __builtin_amdgcn_sched_barrier(0); } while (0)

// ---------------------------------------------------------------------------
// k_prep: W fp32 -> bf16, fragment-linear (R12 layout):
// wbf2[((k32*8 + nb)*64 + ln)*8 ..] = W[nb*16 + (ln&15)][k32*32 + (ln>>4)*8 ..+7]
// ---------------------------------------------------------------------------
__global__ __launch_bounds__(256) void k_prep(const float* __restrict__ Wt,
                                              const float* __restrict__ Wn,
                                              unsigned short* __restrict__ wbf2,
                                              float* __restrict__ sums) {
    const int gid = blockIdx.x * 256 + threadIdx.x;   // 32768 threads
    if (blockIdx.x == 0 && threadIdx.x < 128) sums[threadIdx.x] = 0.f;

    const int ln  = gid & 63;
    const int nb  = (gid >> 6) & 7;
    const int k32 = gid >> 9;
    const int row = nb * 16 + (ln & 15);
    const int col = k32 * 32 + (ln >> 4) * 8;
    const float* src = (row < NE) ? (Wt + (size_t)row * H + col)
                                  : (Wn + (size_t)(row - NE) * H + col);
    float4 v0 = *(const float4*)src;
    float4 v1 = *(const float4*)(src + 4);
    us8 o;
    o[0] = f2bf(v0.x); o[1] = f2bf(v0.y); o[2] = f2bf(v0.z); o[3] = f2bf(v0.w);
    o[4] = f2bf(v1.x); o[5] = f2bf(v1.y); o[6] = f2bf(v1.z); o[7] = f2bf(v1.w);
    *(us8*)(wbf2 + (size_t)gid * 8) = o;
}

// ---------------------------------------------------------------------------
// k_main: R14 structure + NT on the X stream. 256 blocks x 256 thr = 4 waves;
// wave wm = 16 tokens x 128 cols x FULL K (64 steps of 32), no K-combine.
// All 4 waves walk the SAME rotated B-sequence; X loads are non-temporal so
// L1 holds only the 24 KB B-window (8 KB x depth-3) -> wave 0 misses to L2,
// waves 1-3 hit L1 -> per-CU L2 B-request traffic ~/4.
// Inner step = R8/R12-verbatim: 10 asm loads (8 B + 2 X-nt), depth-3 slots,
// WAITV(20/10/0), per-block K-rotation s0=(blk>>3)&63.
// ---------------------------------------------------------------------------
__global__ __launch_bounds__(256, 1) void k_main(const float* __restrict__ X,
                                                 const unsigned short* __restrict__ wbf2,
                                                 const float* __restrict__ noise,
                                                 float* __restrict__ sumraw,
                                                 float* __restrict__ sumsoft) {
    __shared__ float epf[TOKB * 68];  // weight[64][68] (17.4 KB)
    __shared__ float lsoft[NE];

    const int tid  = threadIdx.x;
    const int wid  = tid >> 6;
    const int lane = tid & 63;
    const int wm   = wid;             // token group (16 tokens), 4 waves
    const int lr   = lane & 15;
    const int lg   = lane >> 4;
    const int t0   = blockIdx.x * TOKB;
    const int s0   = (blockIdx.x >> 3) & 63;   // per-block K rotation

    if (tid < NE) lsoft[tid] = 0.f;

    const float* xp = X + (size_t)(t0 + wm * 16 + lr) * H + lg * 8;
    const unsigned short* bp0 = wbf2 + (size_t)lane * 8;

    f32x4 acc[8];
    #pragma unroll
    for (int i = 0; i < 8; ++i) acc[i] = (f32x4){0.f, 0.f, 0.f, 0.f};

    float4 xb[3][2];                  // X depth-3 (24 VGPR)
    us8    bb[3][8];                  // B depth-3 (96 VGPR)

    // issue rotated step sv into slot: 8 B loads then 2 X-nt loads (10 VMEM)
    #define ISSUE(slot, sv)                                                  \
        do {                                                                 \
            const unsigned short* bA = bp0 + (size_t)(sv) * 4096;            \
            const unsigned short* bB = bA + 2048;                            \
            GLOAD_F4(bb[slot][0], bA, 0);                                    \
            GLOAD_F4(bb[slot][1], bA, 1024);                                 \
            GLOAD_F4(bb[slot][2], bA, 2048);                                 \
            GLOAD_F4(bb[slot][3], bA, 3072);                                 \
            GLOAD_F4(bb[slot][4], bB, 0);                                    \
            GLOAD_F4(bb[slot][5], bB, 1024);                                 \
            GLOAD_F4(bb[slot][6], bB, 2048);                                 \
            GLOAD_F4(bb[slot][7], bB, 3072);                                 \
            const float* xA = xp + (size_t)(sv) * 32;                        \
            GLOAD_F4_NT(xb[slot][0], xA, 0);                                 \
            GLOAD_F4_NT(xb[slot][1], xA, 16);                                \
        } while (0)

    ISSUE(0, s0);
    ISSUE(1, (s0 + 1) & 63);
    ISSUE(2, (s0 + 2) & 63);

    #pragma unroll
    for (int j = 0; j < STEPS; ++j) {
        const int slot = j % 3;       // static after unroll
        if (j < STEPS - 2)       WAITV(20);   // step j's 10 oldest done
        else if (j == STEPS - 2) WAITV(10);
        else                     WAITV(0);

        float4 c0 = xb[slot][0], c1 = xb[slot][1];
        bf16x8 af;
        af[0] = (__bf16)c0.x; af[1] = (__bf16)c0.y;
        af[2] = (__bf16)c0.z; af[3] = (__bf16)c0.w;
        af[4] = (__bf16)c1.x; af[5] = (__bf16)c1.y;
        af[6] = (__bf16)c1.z; af[7] = (__bf16)c1.w;
        #pragma unroll
        for (int nb = 0; nb < 8; ++nb) {
            bf16x8 bfr = __builtin_bit_cast(bf16x8, bb[slot][nb]);
            acc[nb] = __builtin_amdgcn_mfma_f32_16x16x32_bf16(af, bfr, acc[nb], 0, 0, 0);
        }
        if (j + 3 < STEPS) ISSUE(slot, (s0 + j + 3) & 63);
    }
    #undef ISSUE

    // ---- gate: weight = logit_t + softplus(logit_n) * noise[e] (wave-local,
    // full K in acc -> no combine). C/D layout: expert col = lane&15 (+nb*16),
    // token row = wm*16 + (lane>>4)*4 + r.
    {
        float nz[4];
        #pragma unroll
        for (int nb = 0; nb < 4; ++nb) nz[nb] = noise[nb * 16 + lr];
        #pragma unroll
        for (int nb = 0; nb < 4; ++nb)
            #pragma unroll
            for (int r = 0; r < 4; ++r) {
                float lt  = acc[nb][r];
                float lnv = acc[nb + 4][r];
                float sp  = fmaxf(lnv, 0.f) + log1pf(expf(-fabsf(lnv)));
                epf[(wm * 16 + lg * 4 + r) * 68 + nb * 16 + lr] = lt + sp * nz[nb];
            }
    }
    __syncthreads();

    // ---- per-token top-8 + masked softmax (threads 0..63, one token each) ----
    if (tid < TOKB) {
        float tv[KTOP]; int ti[KTOP];
        #pragma unroll
        for (int q = 0; q < KTOP; ++q) { tv[q] = -INFINITY; ti[q] = 0; }
        for (int e = 0; e < NE; ++e) {
            float cv = epf[tid * 68 + e]; int ci = e;
            #pragma unroll
            for (int q = 0; q < KTOP; ++q) {
                if (cv > tv[q]) {
                    float t_ = tv[q]; int i_ = ti[q];
                    tv[q] = cv; ti[q] = ci;
                    cv = t_; ci = i_;
                }
            }
        }
        float m = tv[0], den = 0.f, pr[KTOP];
        #pragma unroll
        for (int q = 0; q < KTOP; ++q) { pr[q] = expf(tv[q] - m); den += pr[q]; }
        float inv = 1.f / den;
        #pragma unroll
        for (int q = 0; q < KTOP; ++q) atomicAdd(&lsoft[ti[q]], pr[q] * inv);
    }
    __syncthreads();

    // ---- per-expert sums -> global atomics (threads 0..63) ----
    if (tid < NE) {
        float s = 0.f;
        #pragma unroll
        for (int t = 0; t < TOKB; ++t) s += epf[t * 68 + tid];
        atomicAdd(&sumraw[tid], s);
        atomicAdd(&sumsoft[tid], lsoft[tid]);
    }
}

// ---------------------------------------------------------------------------
// k_final: mean top-8 + softmax -> out[0..15]; CV^2 -> out[16]
// ---------------------------------------------------------------------------
__global__ void k_final(const float* __restrict__ sumraw,
                        const float* __restrict__ sumsoft,
                        float* __restrict__ out) {
    if (threadIdx.x != 0 || blockIdx.x != 0) return;

    float mw[NE];
    for (int e = 0; e < NE; ++e) mw[e] = sumraw[e] * (1.f / (float)NTOK);

    float tv[KTOP]; int ti[KTOP];
    for (int q = 0; q < KTOP; ++q) { tv[q] = -INFINITY; ti[q] = 0; }
    for (int e = 0; e < NE; ++e) {
        float cv = mw[e]; int ci = e;
        for (int q = 0; q < KTOP; ++q) {
            if (cv > tv[q]) {
                float t_ = tv[q]; int i_ = ti[q];
                tv[q] = cv; ti[q] = ci;
                cv = t_; ci = i_;
            }
        }
    }
    float m = tv[0], den = 0.f, pr[KTOP];
    for (int q = 0; q < KTOP; ++q) { pr[q] = expf(tv[q] - m); den += pr[q]; }
    for (int q = 0; q < KTOP; ++q) {
        out[q] = pr[q] / den;
        out[KTOP + q] = (float)ti[q];
    }

    float s = 0.f;
    for (int e = 0; e < NE; ++e) s += sumsoft[e];
    float mean = s / (float)NE;
    float var = 0.f;
    for (int e = 0; e < NE; ++e) { float d = sumsoft[e] - mean; var += d * d; }
    var /= (float)(NE - 1);  // ddof=1
    out[16] = var / (mean * mean);
}

extern "C" void kernel_launch(void* const* d_in, const int* in_sizes, int n_in,
                              void* d_out, int out_size, void* d_ws, size_t ws_size,
                              hipStream_t stream) {
    (void)in_sizes; (void)n_in; (void)out_size; (void)ws_size;
    const float* x     = (const float*)d_in[0];
    const float* wt    = (const float*)d_in[1];
    const float* wn    = (const float*)d_in[2];
    const float* noise = (const float*)d_in[3];
    float* out = (float*)d_out;

    float* sumraw  = (float*)d_ws;                          // [64]
    float* sumsoft = sumraw + NE;                           // [64]
    unsigned short* wbf2 = (unsigned short*)(sumsoft + NE); // [128][2048] bf16 frag-linear

    k_prep<<<128, 256, 0, stream>>>(wt, wn, wbf2, sumraw);
    k_main<<<256, 256, 0, stream>>>(x, wbf2, noise, sumraw, sumsoft);
    k_final<<<1, 64, 0, stream>>>(sumraw, sumsoft, out);
}

// Round 18
// 99.078 us; speedup vs baseline: 1.0383x; 1.0383x over previous
//
#include <hip/hip_runtime.h>
#include <math.h>

#define H     2048
#define NE    64
#define KTOP  8
#define NTOK  16384
#define TOKB  64
#define STEPS 32                       // K / 64

typedef __attribute__((ext_vector_type(8))) __bf16 bf16x8;
typedef __attribute__((ext_vector_type(8))) unsigned short us8;
typedef __attribute__((ext_vector_type(4))) float f32x4;

__device__ __forceinline__ unsigned short f2bf(float f) {
    unsigned u = __builtin_bit_cast(unsigned, f);
    return (unsigned short)((u + 0x7FFFu + ((u >> 16) & 1u)) >> 16);  // RNE
}

// ---------------------------------------------------------------------------
// k_prep: W fp32 -> bf16, fragment-linear:
// wbf2[((k32*8 + nb)*64 + ln)*8 ..] = W[nb*16 + (ln&15)][k32*32 + (ln>>4)*8 ..+7]
// A 64-K-step tile (k32 = 2s, 2s+1) is a CONTIGUOUS 16 KB block.
// ---------------------------------------------------------------------------
__global__ __launch_bounds__(256) void k_prep(const float* __restrict__ Wt,
                                              const float* __restrict__ Wn,
                                              unsigned short* __restrict__ wbf2,
                                              float* __restrict__ sums) {
    const int gid = blockIdx.x * 256 + threadIdx.x;   // 32768 threads
    if (blockIdx.x == 0 && threadIdx.x < 128) sums[threadIdx.x] = 0.f;

    const int ln  = gid & 63;
    const int nb  = (gid >> 6) & 7;
    const int k32 = gid >> 9;
    const int row = nb * 16 + (ln & 15);
    const int col = k32 * 32 + (ln >> 4) * 8;
    const float* src = (row < NE) ? (Wt + (size_t)row * H + col)
                                  : (Wn + (size_t)(row - NE) * H + col);
    float4 v0 = *(const float4*)src;
    float4 v1 = *(const float4*)(src + 4);
    us8 o;
    o[0] = f2bf(v0.x); o[1] = f2bf(v0.y); o[2] = f2bf(v0.z); o[3] = f2bf(v0.w);
    o[4] = f2bf(v1.x); o[5] = f2bf(v1.y); o[6] = f2bf(v1.z); o[7] = f2bf(v1.w);
    *(us8*)(wbf2 + (size_t)gid * 8) = o;
}

// ---------------------------------------------------------------------------
// k_main: R6 structure VERBATIM + per-block K-step ROTATION (single change).
// 256 blocks x 512 thr = 8 waves (4 wm x 2 wn), TOKB=64, BK=64, 32 steps,
// double-buffered LDS via global_load_lds (16B), one barrier per step.
// Rotation: block walks sv=(s0+s)&31, s0=(blk>>3)&31 -> the 32 blocks per XCD
// request DIFFERENT B windows at every instant (kills the lockstep hot-window
// that R12 proved costs ~6x effective latency). K-sum commutes.
// ---------------------------------------------------------------------------
__global__ __launch_bounds__(512, 2) void k_main(const float* __restrict__ X,
                                                 const unsigned short* __restrict__ wbf2,
                                                 const float* __restrict__ noise,
                                                 float* __restrict__ sumraw,
                                                 float* __restrict__ sumsoft) {
    __shared__ __align__(16) float Al[2][TOKB][64];                 // 32 KB
    __shared__ __align__(16) unsigned short Bl[2][2][8][64][8];     // 32 KB
    __shared__ float lsoft[NE];

    const int tid  = threadIdx.x;
    const int wid  = tid >> 6;
    const int lane = tid & 63;
    const int wm   = wid & 3;
    const int wn   = wid >> 2;
    const int lr   = lane & 15;
    const int lg   = lane >> 4;
    const int t0   = blockIdx.x * TOKB;
    const int s0   = (blockIdx.x >> 3) & 31;   // per-block K rotation

    if (tid < NE) lsoft[tid] = 0.f;

    // A stage (rotated step sv): source column pre-swizzled (cs = c ^ (r&15));
    // dest lane-linear so global_load_lds is legal; read-side XOR un-swizzles.
    auto stageA = [&](int buf, int sv) {
        #pragma unroll
        for (int i = 0; i < 2; ++i) {
            int f = tid + i * 512;               // [0,1024)
            int r = f >> 4, c = f & 15;
            int cs = c ^ (r & 15);
            const float* src = X + (size_t)(t0 + r) * H + sv * 64 + cs * 4;
            float* dst = &Al[buf][0][0] + (size_t)f * 4;
            __builtin_amdgcn_global_load_lds(
                (const __attribute__((address_space(1))) void*)src,
                (__attribute__((address_space(3))) void*)dst, 16, 0, 0);
        }
    };
    // B stage (rotated step sv): contiguous 16 KB -> contiguous LDS
    auto stageB = [&](int buf, int sv) {
        #pragma unroll
        for (int i = 0; i < 2; ++i) {
            int f = tid + i * 512;               // [0,1024)
            const unsigned short* src = wbf2 + (size_t)sv * 8192 + (size_t)f * 8;
            unsigned short* dst = &Bl[buf][0][0][0][0] + (size_t)f * 8;
            __builtin_amdgcn_global_load_lds(
                (const __attribute__((address_space(1))) void*)src,
                (__attribute__((address_space(3))) void*)dst, 16, 0, 0);
        }
    };

    f32x4 acc[4];
    #pragma unroll
    for (int j = 0; j < 4; ++j) acc[j] = (f32x4){0.f, 0.f, 0.f, 0.f};

    const int nbg0 = wn * 2;                     // col fragments: Wt pair
    const int r_a  = wm * 16 + lr;               // A row this lane reads
    const int msk  = r_a & 15;

    stageA(0, s0);
    stageB(0, s0);

    for (int s = 0; s < STEPS; ++s) {
        const int buf = s & 1;
        __syncthreads();                         // staged buf ready (drains vmcnt)
        if (s + 1 < STEPS) {
            const int svn = (s0 + s + 1) & 31;
            stageA(buf ^ 1, svn); stageB(buf ^ 1, svn);
        }
        #pragma unroll
        for (int kk = 0; kk < 2; ++kk) {
            const int c0 = kk * 8 + lg * 2;
            f32x4 alo = *(const f32x4*)&Al[buf][r_a][((c0    ) ^ msk) * 4];
            f32x4 ahi = *(const f32x4*)&Al[buf][r_a][((c0 + 1) ^ msk) * 4];
            bf16x8 af;
            af[0] = (__bf16)alo[0]; af[1] = (__bf16)alo[1];
            af[2] = (__bf16)alo[2]; af[3] = (__bf16)alo[3];
            af[4] = (__bf16)ahi[0]; af[5] = (__bf16)ahi[1];
            af[6] = (__bf16)ahi[2]; af[7] = (__bf16)ahi[3];
            #pragma unroll
            for (int j = 0; j < 4; ++j) {
                const int nb = (j < 2) ? (nbg0 + j) : (4 + nbg0 + (j - 2));
                bf16x8 bfr = *(const bf16x8*)&Bl[buf][kk][nb][lane][0];
                acc[j] = __builtin_amdgcn_mfma_f32_16x16x32_bf16(af, bfr, acc[j], 0, 0, 0);
            }
        }
    }

    __syncthreads();                             // all compute done; Al reusable
    float* epf = &Al[0][0][0];                   // ep[64][68] aliased (17.4 KB)

    // ---- gate: weight = logit_t + softplus(logit_n) * noise[e]  (wave-local) ----
    {
        float nz0 = noise[wn * 32 + lr];
        float nz1 = noise[wn * 32 + 16 + lr];
        #pragma unroll
        for (int j = 0; j < 2; ++j) {
            float nz = j ? nz1 : nz0;
            #pragma unroll
            for (int r = 0; r < 4; ++r) {
                float lt  = acc[j][r];
                float lnv = acc[j + 2][r];
                float sp  = fmaxf(lnv, 0.f) + log1pf(expf(-fabsf(lnv)));
                epf[(wm * 16 + lg * 4 + r) * 68 + wn * 32 + j * 16 + lr] = lt + sp * nz;
            }
        }
    }
    __syncthreads();

    // ---- per-token top-8 + masked softmax (threads 0..63, one token each) ----
    if (tid < TOKB) {
        float tv[KTOP]; int ti[KTOP];
        #pragma unroll
        for (int q = 0; q < KTOP; ++q) { tv[q] = -INFINITY; ti[q] = 0; }
        for (int e = 0; e < NE; ++e) {
            float cv = epf[tid * 68 + e]; int ci = e;
            #pragma unroll
            for (int q = 0; q < KTOP; ++q) {
                if (cv > tv[q]) {
                    float t_ = tv[q]; int i_ = ti[q];
                    tv[q] = cv; ti[q] = ci;
                    cv = t_; ci = i_;
                }
            }
        }
        float m = tv[0], den = 0.f, pr[KTOP];
        #pragma unroll
        for (int q = 0; q < KTOP; ++q) { pr[q] = expf(tv[q] - m); den += pr[q]; }
        float inv = 1.f / den;
        #pragma unroll
        for (int q = 0; q < KTOP; ++q) atomicAdd(&lsoft[ti[q]], pr[q] * inv);
    }
    __syncthreads();

    // ---- per-expert sums -> global atomics (threads 0..63) ----
    if (tid < NE) {
        float s = 0.f;
        #pragma unroll
        for (int t = 0; t < TOKB; ++t) s += epf[t * 68 + tid];
        atomicAdd(&sumraw[tid], s);
        atomicAdd(&sumsoft[tid], lsoft[tid]);
    }
}

// ---------------------------------------------------------------------------
// k_final: mean top-8 + softmax -> out[0..15]; CV^2 -> out[16]
// ---------------------------------------------------------------------------
__global__ void k_final(const float* __restrict__ sumraw,
                        const float* __restrict__ sumsoft,
                        float* __restrict__ out) {
    if (threadIdx.x != 0 || blockIdx.x != 0) return;

    float mw[NE];
    for (int e = 0; e < NE; ++e) mw[e] = sumraw[e] * (1.f / (float)NTOK);

    float tv[KTOP]; int ti[KTOP];
    for (int q = 0; q < KTOP; ++q) { tv[q] = -INFINITY; ti[q] = 0; }
    for (int e = 0; e < NE; ++e) {
        float cv = mw[e]; int ci = e;
        for (int q = 0; q < KTOP; ++q) {
            if (cv > tv[q]) {
                float t_ = tv[q]; int i_ = ti[q];
                tv[q] = cv; ti[q] = ci;
                cv = t_; ci = i_;
            }
        }
    }
    float m = tv[0], den = 0.f, pr[KTOP];
    for (int q = 0; q < KTOP; ++q) { pr[q] = expf(tv[q] - m); den += pr[q]; }
    for (int q = 0; q < KTOP; ++q) {
        out[q] = pr[q] / den;
        out[KTOP + q] = (float)ti[q];
    }

    float s = 0.f;
    for (int e = 0; e < NE; ++e) s += sumsoft[e];
    float mean = s / (float)NE;
    float var = 0.f;
    for (int e = 0; e < NE; ++e) { float d = sumsoft[e] - mean; var += d * d; }
    var /= (float)(NE - 1);  // ddof=1
    out[16] = var / (mean * mean);
}

extern "C" void kernel_launch(void* const* d_in, const int* in_sizes, int n_in,
                              void* d_out, int out_size, void* d_ws, size_t ws_size,
                              hipStream_t stream) {
    (void)in_sizes; (void)n_in; (void)out_size; (void)ws_size;
    const float* x     = (const float*)d_in[0];
    const float* wt    = (const float*)d_in[1];
    const float* wn    = (const float*)d_in[2];
    const float* noise = (const float*)d_in[3];
    float* out = (float*)d_out;

    float* sumraw  = (float*)d_ws;                          // [64]
    float* sumsoft = sumraw + NE;                           // [64]
    unsigned short* wbf2 = (unsigned short*)(sumsoft + NE); // [128][2048] bf16 frag-linear

    k_prep<<<128, 256, 0, stream>>>(wt, wn, wbf2, sumraw);
    k_main<<<256, 512, 0, stream>>>(x, wbf2, noise, sumraw, sumsoft);
    k_final<<<1, 64, 0, stream>>>(sumraw, sumsoft, out);
}

// Round 19
// 87.916 us; speedup vs baseline: 1.1701x; 1.1270x over previous
//
#include <hip/hip_runtime.h>
#include <math.h>

#define H     2048
#define NE    64
#define KTOP  8
#define NTOK  16384
#define TOKB  64
#define STEPS 32                       // K-half (1024) / 32

typedef __attribute__((ext_vector_type(8))) __bf16 bf16x8;
typedef __attribute__((ext_vector_type(8))) unsigned short us8;
typedef __attribute__((ext_vector_type(4))) float f32x4;

__device__ __forceinline__ unsigned short f2bf(float f) {
    unsigned u = __builtin_bit_cast(unsigned, f);
    return (unsigned short)((u + 0x7FFFu + ((u >> 16) & 1u)) >> 16);  // RNE
}

// volatile asm global loads: compiler cannot sink/reorder/drain them.
#define GLOAD_F4(dst, ptr, OFF)                                        \
    asm volatile("global_load_dwordx4 %0, %1, off offset:%2"           \
                 : "=v"(dst) : "v"(ptr), "i"(OFF))
// non-temporal: X has zero reuse; keep it out of L1 so B can dedup there
#define GLOAD_F4_NT(dst, ptr, OFF)                                     \
    asm volatile("global_load_dwordx4 %0, %1, off offset:%2 nt"        \
                 : "=v"(dst) : "v"(ptr), "i"(OFF))
#define WAITV(N)                                                       \
    do { asm volatile("s_waitcnt vmcnt(%0)" :: "i"(N));                \
         __builtin_amdgcn_sched_barrier(0); } while (0)

// ---------------------------------------------------------------------------
// k_prep: W fp32 -> bf16, fragment-linear (R12 layout):
// wbf2[((k32*8 + nb)*64 + ln)*8 ..] = W[nb*16 + (ln&15)][k32*32 + (ln>>4)*8 ..+7]
// 256 blocks x 128 thr (same 32768 threads, more block parallelism).
// ---------------------------------------------------------------------------
__global__ __launch_bounds__(128) void k_prep(const float* __restrict__ Wt,
                                              const float* __restrict__ Wn,
                                              unsigned short* __restrict__ wbf2,
                                              float* __restrict__ sums) {
    const int gid = blockIdx.x * 128 + threadIdx.x;   // 32768 threads
    if (blockIdx.x == 0 && threadIdx.x < 128) sums[threadIdx.x] = 0.f;

    const int ln  = gid & 63;
    const int nb  = (gid >> 6) & 7;
    const int k32 = gid >> 9;
    const int row = nb * 16 + (ln & 15);
    const int col = k32 * 32 + (ln >> 4) * 8;
    const float* src = (row < NE) ? (Wt + (size_t)row * H + col)
                                  : (Wn + (size_t)(row - NE) * H + col);
    float4 v0 = *(const float4*)src;
    float4 v1 = *(const float4*)(src + 4);
    us8 o;
    o[0] = f2bf(v0.x); o[1] = f2bf(v0.y); o[2] = f2bf(v0.z); o[3] = f2bf(v0.w);
    o[4] = f2bf(v1.x); o[5] = f2bf(v1.y); o[6] = f2bf(v1.z); o[7] = f2bf(v1.w);
    *(us8*)(wbf2 + (size_t)gid * 8) = o;
}

// ---------------------------------------------------------------------------
// k_main: R12 VERBATIM (best measured: ~72 us) + NT on X loads only.
// 256 blocks x 512 thr = 8 waves: wave (wm=wid&3, kp=wid>>2) = 16 tokens x
// 128 cols x K-half [kp*1024,+1024), 32 steps of K=32, 10 loads/step
// (8 B + 2 X-nt), depth-3 slots, WAITV(20/10/0), per-block K-rotation
// s0=(blk>>3)&31. No LDS/barriers in the loop.
// Epilogue: 2-way K-combine in LDS -> gate -> top8/softmax -> atomics.
// ---------------------------------------------------------------------------
__global__ __launch_bounds__(512, 2) void k_main(const float* __restrict__ X,
                                                 const unsigned short* __restrict__ wbf2,
                                                 const float* __restrict__ noise,
                                                 float* __restrict__ sumraw,
                                                 float* __restrict__ sumsoft) {
    __shared__ float cb[4][2048];     // kp=1 acc dump per wm (32 KB)
    __shared__ float epf[TOKB * 68];  // weight[64][68] (17.4 KB)
    __shared__ float lsoft[NE];

    const int tid  = threadIdx.x;
    const int wid  = tid >> 6;
    const int lane = tid & 63;
    const int wm   = wid & 3;         // token group (16 tokens)
    const int kp   = wid >> 2;        // K half
    const int lr   = lane & 15;
    const int lg   = lane >> 4;
    const int t0   = blockIdx.x * TOKB;
    const int s0   = (blockIdx.x >> 3) & 31;   // per-block K rotation

    if (tid < NE) lsoft[tid] = 0.f;

    const float* xp = X + (size_t)(t0 + wm * 16 + lr) * H + kp * 1024 + lg * 8;
    const unsigned short* bp0 = wbf2 + (size_t)kp * 32 * 4096 + (size_t)lane * 8;

    f32x4 acc[8];
    #pragma unroll
    for (int i = 0; i < 8; ++i) acc[i] = (f32x4){0.f, 0.f, 0.f, 0.f};

    float4 xb[3][2];                  // X depth-3 (24 VGPR)
    us8    bb[3][8];                  // B depth-3 (96 VGPR)

    // issue rotated step sv into slot: 8 B loads then 2 X-nt loads (10 VMEM)
    #define ISSUE(slot, sv)                                                  \
        do {                                                                 \
            const unsigned short* bA = bp0 + (size_t)(sv) * 4096;            \
            const unsigned short* bB = bA + 2048;                            \
            GLOAD_F4(bb[slot][0], bA, 0);                                    \
            GLOAD_F4(bb[slot][1], bA, 1024);                                 \
            GLOAD_F4(bb[slot][2], bA, 2048);                                 \
            GLOAD_F4(bb[slot][3], bA, 3072);                                 \
            GLOAD_F4(bb[slot][4], bB, 0);                                    \
            GLOAD_F4(bb[slot][5], bB, 1024);                                 \
            GLOAD_F4(bb[slot][6], bB, 2048);                                 \
            GLOAD_F4(bb[slot][7], bB, 3072);                                 \
            const float* xA = xp + (size_t)(sv) * 32;                        \
            GLOAD_F4_NT(xb[slot][0], xA, 0);                                 \
            GLOAD_F4_NT(xb[slot][1], xA, 16);                                \
        } while (0)

    ISSUE(0, (s0 + 0) & 31);
    ISSUE(1, (s0 + 1) & 31);
    ISSUE(2, (s0 + 2) & 31);

    #pragma unroll
    for (int j = 0; j < STEPS; ++j) {
        const int slot = j % 3;       // static after unroll
        if (j < STEPS - 2)       WAITV(20);   // step j's 10 oldest done
        else if (j == STEPS - 2) WAITV(10);
        else                     WAITV(0);

        float4 c0 = xb[slot][0], c1 = xb[slot][1];
        bf16x8 af;
        af[0] = (__bf16)c0.x; af[1] = (__bf16)c0.y;
        af[2] = (__bf16)c0.z; af[3] = (__bf16)c0.w;
        af[4] = (__bf16)c1.x; af[5] = (__bf16)c1.y;
        af[6] = (__bf16)c1.z; af[7] = (__bf16)c1.w;
        #pragma unroll
        for (int nb = 0; nb < 8; ++nb) {
            bf16x8 bfr = __builtin_bit_cast(bf16x8, bb[slot][nb]);
            acc[nb] = __builtin_amdgcn_mfma_f32_16x16x32_bf16(af, bfr, acc[nb], 0, 0, 0);
        }
        if (j + 3 < STEPS) ISSUE(slot, (s0 + j + 3) & 31);
    }
    #undef ISSUE

    // ---- 2-way K combine (kp=1 dumps, kp=0 adds) ----
    if (kp == 1) {
        #pragma unroll
        for (int nb = 0; nb < 8; ++nb)
            #pragma unroll
            for (int r = 0; r < 4; ++r)
                cb[wm][(nb * 4 + r) * 64 + lane] = acc[nb][r];
    }
    __syncthreads();

    if (kp == 0) {
        #pragma unroll
        for (int nb = 0; nb < 8; ++nb)
            #pragma unroll
            for (int r = 0; r < 4; ++r)
                acc[nb][r] += cb[wm][(nb * 4 + r) * 64 + lane];
        float nz[4];
        #pragma unroll
        for (int nb = 0; nb < 4; ++nb) nz[nb] = noise[nb * 16 + lr];
        // gate: weight = logit_t + softplus(logit_n) * noise[e]
        // C/D layout: expert col = lane&15 (+nb*16), token row = (lane>>4)*4 + r
        #pragma unroll
        for (int nb = 0; nb < 4; ++nb)
            #pragma unroll
            for (int r = 0; r < 4; ++r) {
                float lt  = acc[nb][r];
                float lnv = acc[nb + 4][r];
                float sp  = fmaxf(lnv, 0.f) + log1pf(expf(-fabsf(lnv)));
                epf[(wm * 16 + lg * 4 + r) * 68 + nb * 16 + lr] = lt + sp * nz[nb];
            }
    }
    __syncthreads();

    // ---- per-token top-8 + masked softmax (threads 0..63, one token each) ----
    if (tid < TOKB) {
        float tv[KTOP]; int ti[KTOP];
        #pragma unroll
        for (int q = 0; q < KTOP; ++q) { tv[q] = -INFINITY; ti[q] = 0; }
        for (int e = 0; e < NE; ++e) {
            float cv = epf[tid * 68 + e]; int ci = e;
            #pragma unroll
            for (int q = 0; q < KTOP; ++q) {
                if (cv > tv[q]) {
                    float t_ = tv[q]; int i_ = ti[q];
                    tv[q] = cv; ti[q] = ci;
                    cv = t_; ci = i_;
                }
            }
        }
        float m = tv[0], den = 0.f, pr[KTOP];
        #pragma unroll
        for (int q = 0; q < KTOP; ++q) { pr[q] = expf(tv[q] - m); den += pr[q]; }
        float inv = 1.f / den;
        #pragma unroll
        for (int q = 0; q < KTOP; ++q) atomicAdd(&lsoft[ti[q]], pr[q] * inv);
    }
    __syncthreads();

    // ---- per-expert sums -> global atomics (threads 0..63) ----
    if (tid < NE) {
        float s = 0.f;
        #pragma unroll
        for (int t = 0; t < TOKB; ++t) s += epf[t * 68 + tid];
        atomicAdd(&sumraw[tid], s);
        atomicAdd(&sumsoft[tid], lsoft[tid]);
    }
}

// ---------------------------------------------------------------------------
// k_final: mean top-8 + softmax -> out[0..15]; CV^2 -> out[16]
// ---------------------------------------------------------------------------
__global__ void k_final(const float* __restrict__ sumraw,
                        const float* __restrict__ sumsoft,
                        float* __restrict__ out) {
    if (threadIdx.x != 0 || blockIdx.x != 0) return;

    float mw[NE];
    for (int e = 0; e < NE; ++e) mw[e] = sumraw[e] * (1.f / (float)NTOK);

    float tv[KTOP]; int ti[KTOP];
    for (int q = 0; q < KTOP; ++q) { tv[q] = -INFINITY; ti[q] = 0; }
    for (int e = 0; e < NE; ++e) {
        float cv = mw[e]; int ci = e;
        for (int q = 0; q < KTOP; ++q) {
            if (cv > tv[q]) {
                float t_ = tv[q]; int i_ = ti[q];
                tv[q] = cv; ti[q] = ci;
                cv = t_; ci = i_;
            }
        }
    }
    float m = tv[0], den = 0.f, pr[KTOP];
    for (int q = 0; q < KTOP; ++q) { pr[q] = expf(tv[q] - m); den += pr[q]; }
    for (int q = 0; q < KTOP; ++q) {
        out[q] = pr[q] / den;
        out[KTOP + q] = (float)ti[q];
    }

    float s = 0.f;
    for (int e = 0; e < NE; ++e) s += sumsoft[e];
    float mean = s / (float)NE;
    float var = 0.f;
    for (int e = 0; e < NE; ++e) { float d = sumsoft[e] - mean; var += d * d; }
    var /= (float)(NE - 1);  // ddof=1
    out[16] = var / (mean * mean);
}

extern "C" void kernel_launch(void* const* d_in, const int* in_sizes, int n_in,
                              void* d_out, int out_size, void* d_ws, size_t ws_size,
                              hipStream_t stream) {
    (void)in_sizes; (void)n_in; (void)out_size; (void)ws_size;
    const float* x     = (const float*)d_in[0];
    const float* wt    = (const float*)d_in[1];
    const float* wn    = (const float*)d_in[2];
    const float* noise = (const float*)d_in[3];
    float* out = (float*)d_out;

    float* sumraw  = (float*)d_ws;                          // [64]
    float* sumsoft = sumraw + NE;                           // [64]
    unsigned short* wbf2 = (unsigned short*)(sumsoft + NE); // [128][2048] bf16 frag-linear

    k_prep<<<256, 128, 0, stream>>>(wt, wn, wbf2, sumraw);
    k_main<<<256, 512, 0, stream>>>(x, wbf2, noise, sumraw, sumsoft);
    k_final<<<1, 64, 0, stream>>>(sumraw, sumsoft, out);
}